// Round 18
// baseline (168.034 us; speedup 1.0000x reference)
//
#include <hip/hip_runtime.h>
#include <hip/hip_bf16.h>
#include <math.h>

typedef _Float16 f16;
typedef __attribute__((ext_vector_type(8))) _Float16 f16x8;
typedef __attribute__((ext_vector_type(16))) float f32x16;

// Problem constants
#define DIMS 256
#define NCODE 1024
#define NPTS 65536          // 64 * 32 * 32

// d_out layout (floats): [0]=loss, [1..16777217)=quantized NCHW (2^24 elems),
// [16777217]=perplexity, [16777218..16842754)=idx as float (65536)
#define OUT_Q_OFF 1
#define OUT_PERP_OFF 16777217
#define OUT_IDX_OFF 16777218

// E hi/lo f16 planes parked inside the (later overwritten) quantized out region.
// Staged order (both planes): per 32-code tile (16384 B), row=code&31 (512 B),
// granule g=dim>>3 at position g^(row&7) -> linear global_load_lds + swizzled ds_read.
#define EHI_F32_OFF 4
#define ELO_F32_OFF (4 + 131072)
#define TILE_BYTES 16384

#define XSTRIDE 132         // fp32 per padded LDS row for X transpose chunks (128 pts + pad)

// Direct HBM/L2 -> LDS copy, 16 B per lane; LDS dest = uniform base + lane*16.
__device__ __forceinline__ void gload_lds16(const void* g, void* l) {
    __builtin_amdgcn_global_load_lds(
        (const __attribute__((address_space(1))) unsigned int*)g,
        (__attribute__((address_space(3))) unsigned int*)l, 16, 0, 0);
}

// ---------------------------------------------------------------------------
// Fused E-prep: split E into f16 hi/lo planes (staged/swizzled order) + ||e||^2.
// One wave per codebook row. 256 blocks x 256 thr (4 waves).
__global__ __launch_bounds__(256) void k_eprep(const float* __restrict__ ew,
                                               char* __restrict__ ehi,
                                               char* __restrict__ elo,
                                               float* __restrict__ enorm) {
    int w = threadIdx.x >> 6;
    int l = threadIdx.x & 63;
    int row = blockIdx.x * 4 + w;
    float4 v = *reinterpret_cast<const float4*>(ew + (size_t)row * DIMS + l * 4);
    float vv[4] = {v.x, v.y, v.z, v.w};
    __align__(8) f16 hh[4];
    __align__(8) f16 ll[4];
    float s = 0.0f;
    #pragma unroll
    for (int e = 0; e < 4; ++e) {
        f16 h = (f16)vv[e];
        hh[e] = h;
        ll[e] = (f16)(vv[e] - (float)h);
        s += vv[e] * vv[e];
    }
    // lane l covers dims 4l..4l+3 -> granule g = l>>1, half (l&1)
    size_t off = (size_t)(row >> 5) * TILE_BYTES + (size_t)(row & 31) * 512
               + (size_t)((((l >> 1) ^ (row & 7)) << 4) + ((l & 1) << 3));
    *reinterpret_cast<float2*>(ehi + off) = *reinterpret_cast<float2*>(hh);
    *reinterpret_cast<float2*>(elo + off) = *reinterpret_cast<float2*>(ll);
    #pragma unroll
    for (int off2 = 32; off2 > 0; off2 >>= 1) s += __shfl_down(s, off2);
    if (l == 0) enorm[row] = s;
}

// ---------------------------------------------------------------------------
// MFMA argmin, ONE 8-wave block per CU (grid 256). NEW: TRIPLE-buffered E with
// counted-vmcnt raw barriers (T3+T4): round rd issues tile rd+2, computes tile
// rd, then waits only vmcnt(4) (tile rd+1 resident; rd+2's loads stay in
// flight across the barrier). Replaces __syncthreads' vmcnt(0)-drain — the
// m233-style 2-phase stall the counters pointed at (all pipes <50%).
__global__ __launch_bounds__(512, 1) void k_argmin_mfma(const float* __restrict__ x,
                                                        const char* __restrict__ ehi,
                                                        const char* __restrict__ elo,
                                                        const float* __restrict__ enorm,
                                                        int* __restrict__ out_idx) {
    __shared__ __align__(16) char smem[3 * 2 * TILE_BYTES];   // 3 bufs x [EH|EL] = 98304 B
    __shared__ float enorm_lds[NCODE];
    float* Xs = (float*)smem;                   // phase 1 reuse: [64][XSTRIDE] fp32 (33792 B)

    const int t = threadIdx.x;                  // 0..511
    const int wave = t >> 6;                    // 0..7
    const int lane = t & 63;
    const int lrow = lane & 31;
    const int lhalf = lane >> 5;

    const int blk = blockIdx.x;                 // 0..255
    const int b = blk >> 2;                     // batch
    const int hw0 = (blk & 3) << 8;             // 256-point slab within batch
    const float* xb = x + (size_t)b * (DIMS * 1024) + hw0;

    // stage enorm into LDS (covered by the phase-1 barriers)
    enorm_lds[t] = enorm[t];
    enorm_lds[t + 512] = enorm[t + 512];

    // ---- Phase 1: build split-f16 A fragments (two 128-point halves) ----
    f16x8 ahi[16], alo[16];
    #pragma unroll
    for (int dc = 0; dc < 4; ++dc) {
        #pragma unroll
        for (int h = 0; h < 2; ++h) {
            __syncthreads();
            // stage 64 dims x 128 pts fp32: 2048 float4 / 512 thr = 4 iters
            #pragma unroll
            for (int i = 0; i < 4; ++i) {
                int id = i * 512 + t;
                int d = id >> 5;                // 0..63
                int p4 = id & 31;               // float4 within the 128-pt half
                float4 v = *reinterpret_cast<const float4*>(
                    xb + (size_t)(dc * 64 + d) * 1024 + h * 128 + p4 * 4);
                *reinterpret_cast<float4*>(&Xs[d * XSTRIDE + p4 * 4]) = v;
            }
            __syncthreads();
            if ((wave >> 2) == h) {
                int p = (wave & 3) * 32 + lrow;
                #pragma unroll
                for (int kcl = 0; kcl < 4; ++kcl) {
                    f16x8 hh, ll;
                    #pragma unroll
                    for (int e = 0; e < 8; ++e) {
                        float xv = Xs[(kcl * 16 + lhalf * 8 + e) * XSTRIDE + p];
                        f16 hi = (f16)xv;
                        hh[e] = hi;
                        ll[e] = (f16)(xv - (float)hi);
                    }
                    ahi[dc * 4 + kcl] = hh;
                    alo[dc * 4 + kcl] = ll;
                }
            }
        }
    }
    __syncthreads();    // all waves done reading Xs before buf0/buf1 staging lands

    // ---- staging assignment: waves 0-3 -> EH plane, waves 4-7 -> EL plane;
    //      each wave stages quarter (wave&3) of a 16 KB plane (4 KB = 4 loads).
    const int plane = wave >> 2;
    const char* gplane = plane ? elo : ehi;
    const int pl_off = plane * TILE_BYTES;           // within a buffer
    const int woff = (wave & 3) * 4096;

    // ---- Prologue: stage tiles 0,1 into buffers 0,1; wait tile0 only ----
    #pragma unroll
    for (int k = 0; k < 2; ++k) {
        #pragma unroll
        for (int i = 0; i < 4; ++i) {
            int off = woff + i * 1024;
            gload_lds16(gplane + (size_t)k * TILE_BYTES + off + lane * 16,
                        smem + k * (2 * TILE_BYTES) + pl_off + off);
        }
    }
    asm volatile("s_waitcnt vmcnt(4)" ::: "memory");   // tile0 (oldest 4) resident
    __builtin_amdgcn_s_barrier();                       // all waves' tile0 resident

    float bestv[16];
    int besti[16];
    #pragma unroll
    for (int r = 0; r < 16; ++r) { bestv[r] = -3.4e38f; besti[r] = 0; }

    // ---- Main loop: 32 rounds; counted-vmcnt pipeline, deferred scoring ----
#define ROUND_BODY(ACC_CUR, ACC_PREV, RD)                                         \
    {                                                                             \
        const int rd_ = (RD);                                                     \
        const int cur_ = rd_ % 3;                                                 \
        if (rd_ + 2 < 32) {                                                       \
            const int nx_ = (rd_ + 2) % 3;                                        \
            const char* gp_ = gplane + (size_t)(rd_ + 2) * TILE_BYTES;            \
            char* lp_ = smem + nx_ * (2 * TILE_BYTES) + pl_off;                   \
            _Pragma("unroll")                                                     \
            for (int i_ = 0; i_ < 4; ++i_) {                                      \
                int off_ = woff + i_ * 1024;                                      \
                gload_lds16(gp_ + off_ + lane * 16, lp_ + off_);                  \
            }                                                                     \
        }                                                                         \
        const char* EHb_ = smem + cur_ * (2 * TILE_BYTES);                        \
        const char* ELb_ = EHb_ + TILE_BYTES;                                     \
        float nh_ = -0.5f * enorm_lds[rd_ * 32 + lrow];                           \
        _Pragma("unroll")                                                         \
        for (int r_ = 0; r_ < 16; ++r_) ACC_CUR[r_] = nh_;                        \
        __builtin_amdgcn_s_setprio(1);                                            \
        _Pragma("unroll")                                                         \
        for (int kc_ = 0; kc_ < 16; ++kc_) {                                      \
            int g_ = kc_ * 2 + lhalf;                                             \
            int ra_ = lrow * 512 + ((g_ ^ (lrow & 7)) << 4);                      \
            f16x8 bh_ = *reinterpret_cast<const f16x8*>(EHb_ + ra_);              \
            f16x8 bl_ = *reinterpret_cast<const f16x8*>(ELb_ + ra_);              \
            ACC_CUR = __builtin_amdgcn_mfma_f32_32x32x16_f16(ahi[kc_], bh_, ACC_CUR, 0, 0, 0); \
            ACC_CUR = __builtin_amdgcn_mfma_f32_32x32x16_f16(ahi[kc_], bl_, ACC_CUR, 0, 0, 0); \
            ACC_CUR = __builtin_amdgcn_mfma_f32_32x32x16_f16(alo[kc_], bh_, ACC_CUR, 0, 0, 0); \
        }                                                                         \
        __builtin_amdgcn_s_setprio(0);                                            \
        if (rd_ > 0) {                                                            \
            const int cw_ = (rd_ - 1) * 32 + lrow;                                \
            _Pragma("unroll")                                                     \
            for (int r_ = 0; r_ < 16; ++r_) {                                     \
                float s_ = ACC_PREV[r_];                                          \
                if (s_ > bestv[r_]) { bestv[r_] = s_; besti[r_] = cw_; }          \
            }                                                                     \
        }                                                                         \
        /* counted wait: tile rd+1 resident (oldest 4 of <=8 outstanding); */     \
        /* tile rd+2's loads stay in flight across the raw barrier */             \
        if (rd_ + 2 < 32) asm volatile("s_waitcnt vmcnt(4)" ::: "memory");        \
        else              asm volatile("s_waitcnt vmcnt(0)" ::: "memory");        \
        __builtin_amdgcn_s_barrier();                                             \
    }

    f32x16 accA, accB;
    for (int rr = 0; rr < 16; ++rr) {
        ROUND_BODY(accA, accB, 2 * rr);
        ROUND_BODY(accB, accA, 2 * rr + 1);
    }
    // epilogue: score the final round (rd=31, held in accB)
    {
        int cw = 31 * 32 + lrow;
        #pragma unroll
        for (int r = 0; r < 16; ++r) {
            float s = accB[r];
            if (s > bestv[r]) { bestv[r] = s; besti[r] = cw; }
        }
    }
#undef ROUND_BODY

    // ---- cross-lane argmax reduce over the 32 codes dimension (lrow) ----
    #pragma unroll
    for (int off = 1; off <= 16; off <<= 1) {
        #pragma unroll
        for (int r = 0; r < 16; ++r) {
            float ov = __shfl_xor(bestv[r], off);
            int oi = __shfl_xor(besti[r], off);
            if (ov > bestv[r] || (ov == bestv[r] && oi < besti[r])) {
                bestv[r] = ov;
                besti[r] = oi;
            }
        }
    }
    if (lrow == 0) {
        #pragma unroll
        for (int r = 0; r < 16; ++r) {
            int row = (r & 3) + 8 * (r >> 2) + 4 * lhalf;   // C/D row mapping
            out_idx[blk * 256 + wave * 32 + row] = besti[r];
        }
    }
}

// ---------------------------------------------------------------------------
// Tiled quantize + histogram + idx output (merged; R10-proven, NO fence).
// Block = 64 points, gather the needed E rows once into LDS, stream x (float4)
// / out coalesced. grid 1024, 512 threads.
#define QSTRIDE 258
__global__ __launch_bounds__(512) void k_quant(const float* __restrict__ x,
                                               const float* __restrict__ ew,
                                               const int* __restrict__ idxv,
                                               float* __restrict__ out,
                                               float* __restrict__ loss_acc,
                                               int* __restrict__ counts) {
    __shared__ float Eq[64 * QSTRIDE];          // 66048 B
    __shared__ int ids[64];
    __shared__ int h[NCODE];
    const int t = threadIdx.x;
    const int blk = blockIdx.x;                 // 0..1023
    const int b = blk >> 4;
    const int hw0 = (blk & 15) << 6;

    if (t < 64) ids[t] = idxv[(b << 10) + hw0 + t];
    h[t] = 0;
    if (t < 512) h[t + 512] = 0;
    __syncthreads();

    if (t < 64) atomicAdd(&h[ids[t]], 1);       // completes before next barrier

    // stage 64 gathered E rows: 4096 float4 / 512 thr = 8 iters, coalesced per row
    #pragma unroll
    for (int i = 0; i < 8; ++i) {
        int f = i * 512 + t;                    // float4 id in [64][64]
        int row = f >> 6;
        int c4 = f & 63;
        float4 v = *reinterpret_cast<const float4*>(ew + (size_t)ids[row] * DIMS + c4 * 4);
        float2 lo2 = {v.x, v.y};
        float2 hi2 = {v.z, v.w};
        *reinterpret_cast<float2*>(&Eq[row * QSTRIDE + c4 * 4]) = lo2;
        *reinterpret_cast<float2*>(&Eq[row * QSTRIDE + c4 * 4 + 2]) = hi2;
    }
    __syncthreads();

    // thread handles a float4 of 4 consecutive points (q4) at channel cb + k*32
    const int q4 = t & 15;                      // point-quad: points 4*q4..4*q4+3
    const int cb = t >> 4;                      // 0..31
    const int p = q4 * 4;
    float lsum = 0.0f;
    #pragma unroll
    for (int k = 0; k < 8; ++k) {
        int c = k * 32 + cb;
        unsigned g = ((unsigned)b << 18) | ((unsigned)c << 10) | (unsigned)(hw0 + p);
        float4 xv = *reinterpret_cast<const float4*>(x + g);   // 16B aligned
        float q0 = Eq[(p + 0) * QSTRIDE + c];
        float q1 = Eq[(p + 1) * QSTRIDE + c];
        float q2 = Eq[(p + 2) * QSTRIDE + c];
        float q3 = Eq[(p + 3) * QSTRIDE + c];
        float d0 = q0 - xv.x, d1 = q1 - xv.y, d2 = q2 - xv.z, d3 = q3 - xv.w;
        // out+1+g is not 16B aligned -> scalar stores
        out[OUT_Q_OFF + g + 0] = xv.x + d0;
        out[OUT_Q_OFF + g + 1] = xv.y + d1;
        out[OUT_Q_OFF + g + 2] = xv.z + d2;
        out[OUT_Q_OFF + g + 3] = xv.w + d3;
        lsum += d0 * d0 + d1 * d1 + d2 * d2 + d3 * d3;
    }
    #pragma unroll
    for (int off = 32; off > 0; off >>= 1) lsum += __shfl_down(lsum, off);
    if ((t & 63) == 0) atomicAdd(&loss_acc[blk & 63], lsum);

    // flush histogram (h finalized before the staging barrier) + idx floats
    int v0 = h[t];
    if (v0) atomicAdd(&counts[t], v0);
    if (t < 512) {
        int v1 = h[t + 512];
        if (v1) atomicAdd(&counts[t + 512], v1);
    }
    if (t < 64) out[OUT_IDX_OFF + (b << 10) + hw0 + t] = (float)ids[t];
}

// ---------------------------------------------------------------------------
// Perplexity + final loss.
__global__ __launch_bounds__(256) void k_final(const int* __restrict__ counts,
                                               const float* __restrict__ loss_acc,
                                               float* __restrict__ out) {
    int t = threadIdx.x;
    float s = 0.0f;
    #pragma unroll
    for (int i = 0; i < 4; ++i) {
        int cnt = counts[t + 256 * i];
        float p = (float)cnt * (1.0f / 65536.0f);
        s += p * logf(p + 1e-10f);
    }
    #pragma unroll
    for (int off = 32; off > 0; off >>= 1) s += __shfl_down(s, off);
    __shared__ float wsum[4];
    if ((t & 63) == 0) wsum[t >> 6] = s;
    __syncthreads();
    if (t == 0) {
        float S = wsum[0] + wsum[1] + wsum[2] + wsum[3];
        out[OUT_PERP_OFF] = expf(-S);
        float ls = 0.0f;
        for (int i = 0; i < 64; ++i) ls += loss_acc[i];
        out[0] = 0.25f * (ls * (1.0f / 16777216.0f));
    }
}

// ---------------------------------------------------------------------------
extern "C" void kernel_launch(void* const* d_in, const int* in_sizes, int n_in,
                              void* d_out, int out_size, void* d_ws, size_t ws_size,
                              hipStream_t stream) {
    const float* x = (const float*)d_in[0];    // [64,256,32,32]
    const float* ew = (const float*)d_in[1];   // [1024,256]
    float* out = (float*)d_out;
    float* ws = (float*)d_ws;

    float* loss_acc = ws;                      // 64 floats
    int* counts = (int*)(ws + 64);             // 1024 ints
    float* enorm = ws + 64 + 1024;             // 1024 floats
    int* idxv = (int*)(ws + 64 + 2048);        // 65536 ints

    // f16 hi/lo staged planes parked in the quantized out region (overwritten by k_quant)
    char* ehi = (char*)(out + EHI_F32_OFF);
    char* elo = (char*)(out + ELO_F32_OFF);

    hipMemsetAsync(d_ws, 0, (64 + 1024) * sizeof(float), stream);

    k_eprep<<<256, 256, 0, stream>>>(ew, ehi, elo, enorm);
    k_argmin_mfma<<<256, 512, 0, stream>>>(x, ehi, elo, enorm, idxv);
    k_quant<<<1024, 512, 0, stream>>>(x, ew, idxv, out, loss_acc, counts);
    k_final<<<1, 256, 0, stream>>>(counts, loss_acc, out);
}

// Round 19
// 166.916 us; speedup vs baseline: 1.0067x; 1.0067x over previous
//
#include <hip/hip_runtime.h>
#include <hip/hip_bf16.h>
#include <math.h>

typedef _Float16 f16;
typedef __attribute__((ext_vector_type(8))) _Float16 f16x8;
typedef __attribute__((ext_vector_type(16))) float f32x16;
typedef float4 float4_u __attribute__((aligned(4)));   // dword-aligned vector store

// Problem constants
#define DIMS 256
#define NCODE 1024
#define NPTS 65536          // 64 * 32 * 32

// d_out layout (floats): [0]=loss, [1..16777217)=quantized NCHW (2^24 elems),
// [16777217]=perplexity, [16777218..16842754)=idx as float (65536)
#define OUT_Q_OFF 1
#define OUT_PERP_OFF 16777217
#define OUT_IDX_OFF 16777218

// E hi/lo f16 planes parked inside the (later overwritten) quantized out region.
// Staged order (both planes): per 32-code tile (16384 B), row=code&31 (512 B),
// granule g=dim>>3 at position g^(row&7) -> linear global_load_lds + swizzled ds_read.
#define EHI_F32_OFF 4
#define ELO_F32_OFF (4 + 131072)
#define TILE_BYTES 16384

#define XSTRIDE 132         // fp32 per padded LDS row for X transpose chunks (128 pts + pad)

// Direct HBM/L2 -> LDS copy, 16 B per lane; LDS dest = uniform base + lane*16.
__device__ __forceinline__ void gload_lds16(const void* g, void* l) {
    __builtin_amdgcn_global_load_lds(
        (const __attribute__((address_space(1))) unsigned int*)g,
        (__attribute__((address_space(3))) unsigned int*)l, 16, 0, 0);
}

// ---------------------------------------------------------------------------
// Fused E-prep: split E into f16 hi/lo planes (staged/swizzled order) + ||e||^2.
// One wave per codebook row. 256 blocks x 256 thr (4 waves).
__global__ __launch_bounds__(256) void k_eprep(const float* __restrict__ ew,
                                               char* __restrict__ ehi,
                                               char* __restrict__ elo,
                                               float* __restrict__ enorm) {
    int w = threadIdx.x >> 6;
    int l = threadIdx.x & 63;
    int row = blockIdx.x * 4 + w;
    float4 v = *reinterpret_cast<const float4*>(ew + (size_t)row * DIMS + l * 4);
    float vv[4] = {v.x, v.y, v.z, v.w};
    __align__(8) f16 hh[4];
    __align__(8) f16 ll[4];
    float s = 0.0f;
    #pragma unroll
    for (int e = 0; e < 4; ++e) {
        f16 h = (f16)vv[e];
        hh[e] = h;
        ll[e] = (f16)(vv[e] - (float)h);
        s += vv[e] * vv[e];
    }
    // lane l covers dims 4l..4l+3 -> granule g = l>>1, half (l&1)
    size_t off = (size_t)(row >> 5) * TILE_BYTES + (size_t)(row & 31) * 512
               + (size_t)((((l >> 1) ^ (row & 7)) << 4) + ((l & 1) << 3));
    *reinterpret_cast<float2*>(ehi + off) = *reinterpret_cast<float2*>(hh);
    *reinterpret_cast<float2*>(elo + off) = *reinterpret_cast<float2*>(ll);
    #pragma unroll
    for (int off2 = 32; off2 > 0; off2 >>= 1) s += __shfl_down(s, off2);
    if (l == 0) enorm[row] = s;
}

// ---------------------------------------------------------------------------
// MFMA argmin, ONE 8-wave block per CU (grid 256). TRIPLE-buffered E with
// counted-vmcnt raw barriers; deferred scoring; acc init = -0.5*||e||^2
// (argmax tail). Measured plateau 110 us across 6 structural variants —
// structural floor: CU-wide LDS port under barrier-locked wave phase
// correlation (LDS 50%, MFMA 41%, VALU 20%, none saturated).
__global__ __launch_bounds__(512, 1) void k_argmin_mfma(const float* __restrict__ x,
                                                        const char* __restrict__ ehi,
                                                        const char* __restrict__ elo,
                                                        const float* __restrict__ enorm,
                                                        int* __restrict__ out_idx) {
    __shared__ __align__(16) char smem[3 * 2 * TILE_BYTES];   // 3 bufs x [EH|EL] = 98304 B
    __shared__ float enorm_lds[NCODE];
    float* Xs = (float*)smem;                   // phase 1 reuse: [64][XSTRIDE] fp32 (33792 B)

    const int t = threadIdx.x;                  // 0..511
    const int wave = t >> 6;                    // 0..7
    const int lane = t & 63;
    const int lrow = lane & 31;
    const int lhalf = lane >> 5;

    const int blk = blockIdx.x;                 // 0..255
    const int b = blk >> 2;                     // batch
    const int hw0 = (blk & 3) << 8;             // 256-point slab within batch
    const float* xb = x + (size_t)b * (DIMS * 1024) + hw0;

    // stage enorm into LDS (covered by the phase-1 barriers)
    enorm_lds[t] = enorm[t];
    enorm_lds[t + 512] = enorm[t + 512];

    // ---- Phase 1: build split-f16 A fragments (two 128-point halves) ----
    f16x8 ahi[16], alo[16];
    #pragma unroll
    for (int dc = 0; dc < 4; ++dc) {
        #pragma unroll
        for (int h = 0; h < 2; ++h) {
            __syncthreads();
            // stage 64 dims x 128 pts fp32: 2048 float4 / 512 thr = 4 iters
            #pragma unroll
            for (int i = 0; i < 4; ++i) {
                int id = i * 512 + t;
                int d = id >> 5;                // 0..63
                int p4 = id & 31;               // float4 within the 128-pt half
                float4 v = *reinterpret_cast<const float4*>(
                    xb + (size_t)(dc * 64 + d) * 1024 + h * 128 + p4 * 4);
                *reinterpret_cast<float4*>(&Xs[d * XSTRIDE + p4 * 4]) = v;
            }
            __syncthreads();
            if ((wave >> 2) == h) {
                int p = (wave & 3) * 32 + lrow;
                #pragma unroll
                for (int kcl = 0; kcl < 4; ++kcl) {
                    f16x8 hh, ll;
                    #pragma unroll
                    for (int e = 0; e < 8; ++e) {
                        float xv = Xs[(kcl * 16 + lhalf * 8 + e) * XSTRIDE + p];
                        f16 hi = (f16)xv;
                        hh[e] = hi;
                        ll[e] = (f16)(xv - (float)hi);
                    }
                    ahi[dc * 4 + kcl] = hh;
                    alo[dc * 4 + kcl] = ll;
                }
            }
        }
    }
    __syncthreads();    // all waves done reading Xs before buf0/buf1 staging lands

    // ---- staging assignment: waves 0-3 -> EH plane, waves 4-7 -> EL plane;
    //      each wave stages quarter (wave&3) of a 16 KB plane (4 KB = 4 loads).
    const int plane = wave >> 2;
    const char* gplane = plane ? elo : ehi;
    const int pl_off = plane * TILE_BYTES;           // within a buffer
    const int woff = (wave & 3) * 4096;

    // ---- Prologue: stage tiles 0,1 into buffers 0,1; wait tile0 only ----
    #pragma unroll
    for (int k = 0; k < 2; ++k) {
        #pragma unroll
        for (int i = 0; i < 4; ++i) {
            int off = woff + i * 1024;
            gload_lds16(gplane + (size_t)k * TILE_BYTES + off + lane * 16,
                        smem + k * (2 * TILE_BYTES) + pl_off + off);
        }
    }
    asm volatile("s_waitcnt vmcnt(4)" ::: "memory");   // tile0 (oldest 4) resident
    __builtin_amdgcn_s_barrier();                       // all waves' tile0 resident

    float bestv[16];
    int besti[16];
    #pragma unroll
    for (int r = 0; r < 16; ++r) { bestv[r] = -3.4e38f; besti[r] = 0; }

    // ---- Main loop: 32 rounds; counted-vmcnt pipeline, deferred scoring ----
#define ROUND_BODY(ACC_CUR, ACC_PREV, RD)                                         \
    {                                                                             \
        const int rd_ = (RD);                                                     \
        const int cur_ = rd_ % 3;                                                 \
        if (rd_ + 2 < 32) {                                                       \
            const int nx_ = (rd_ + 2) % 3;                                        \
            const char* gp_ = gplane + (size_t)(rd_ + 2) * TILE_BYTES;            \
            char* lp_ = smem + nx_ * (2 * TILE_BYTES) + pl_off;                   \
            _Pragma("unroll")                                                     \
            for (int i_ = 0; i_ < 4; ++i_) {                                      \
                int off_ = woff + i_ * 1024;                                      \
                gload_lds16(gp_ + off_ + lane * 16, lp_ + off_);                  \
            }                                                                     \
        }                                                                         \
        const char* EHb_ = smem + cur_ * (2 * TILE_BYTES);                        \
        const char* ELb_ = EHb_ + TILE_BYTES;                                     \
        float nh_ = -0.5f * enorm_lds[rd_ * 32 + lrow];                           \
        _Pragma("unroll")                                                         \
        for (int r_ = 0; r_ < 16; ++r_) ACC_CUR[r_] = nh_;                        \
        __builtin_amdgcn_s_setprio(1);                                            \
        _Pragma("unroll")                                                         \
        for (int kc_ = 0; kc_ < 16; ++kc_) {                                      \
            int g_ = kc_ * 2 + lhalf;                                             \
            int ra_ = lrow * 512 + ((g_ ^ (lrow & 7)) << 4);                      \
            f16x8 bh_ = *reinterpret_cast<const f16x8*>(EHb_ + ra_);              \
            f16x8 bl_ = *reinterpret_cast<const f16x8*>(ELb_ + ra_);              \
            ACC_CUR = __builtin_amdgcn_mfma_f32_32x32x16_f16(ahi[kc_], bh_, ACC_CUR, 0, 0, 0); \
            ACC_CUR = __builtin_amdgcn_mfma_f32_32x32x16_f16(ahi[kc_], bl_, ACC_CUR, 0, 0, 0); \
            ACC_CUR = __builtin_amdgcn_mfma_f32_32x32x16_f16(alo[kc_], bh_, ACC_CUR, 0, 0, 0); \
        }                                                                         \
        __builtin_amdgcn_s_setprio(0);                                            \
        if (rd_ > 0) {                                                            \
            const int cw_ = (rd_ - 1) * 32 + lrow;                                \
            _Pragma("unroll")                                                     \
            for (int r_ = 0; r_ < 16; ++r_) {                                     \
                float s_ = ACC_PREV[r_];                                          \
                if (s_ > bestv[r_]) { bestv[r_] = s_; besti[r_] = cw_; }          \
            }                                                                     \
        }                                                                         \
        /* counted wait: tile rd+1 resident (oldest 4 of <=8 outstanding); */     \
        /* tile rd+2's loads stay in flight across the raw barrier */             \
        if (rd_ + 2 < 32) asm volatile("s_waitcnt vmcnt(4)" ::: "memory");        \
        else              asm volatile("s_waitcnt vmcnt(0)" ::: "memory");        \
        __builtin_amdgcn_s_barrier();                                             \
    }

    f32x16 accA, accB;
    for (int rr = 0; rr < 16; ++rr) {
        ROUND_BODY(accA, accB, 2 * rr);
        ROUND_BODY(accB, accA, 2 * rr + 1);
    }
    // epilogue: score the final round (rd=31, held in accB)
    {
        int cw = 31 * 32 + lrow;
        #pragma unroll
        for (int r = 0; r < 16; ++r) {
            float s = accB[r];
            if (s > bestv[r]) { bestv[r] = s; besti[r] = cw; }
        }
    }
#undef ROUND_BODY

    // ---- cross-lane argmax reduce over the 32 codes dimension (lrow) ----
    #pragma unroll
    for (int off = 1; off <= 16; off <<= 1) {
        #pragma unroll
        for (int r = 0; r < 16; ++r) {
            float ov = __shfl_xor(bestv[r], off);
            int oi = __shfl_xor(besti[r], off);
            if (ov > bestv[r] || (ov == bestv[r] && oi < besti[r])) {
                bestv[r] = ov;
                besti[r] = oi;
            }
        }
    }
    if (lrow == 0) {
        #pragma unroll
        for (int r = 0; r < 16; ++r) {
            int row = (r & 3) + 8 * (r >> 2) + 4 * lhalf;   // C/D row mapping
            out_idx[blk * 256 + wave * 32 + row] = besti[r];
        }
    }
}

// ---------------------------------------------------------------------------
// Tiled quantize + histogram + idx output (merged; NO fence). Block = 64 pts,
// gather E rows once into LDS, stream x (float4) / out (unaligned dwordx4).
// grid 1024, 512 threads.
#define QSTRIDE 258
__global__ __launch_bounds__(512) void k_quant(const float* __restrict__ x,
                                               const float* __restrict__ ew,
                                               const int* __restrict__ idxv,
                                               float* __restrict__ out,
                                               float* __restrict__ loss_acc,
                                               int* __restrict__ counts) {
    __shared__ float Eq[64 * QSTRIDE];          // 66048 B
    __shared__ int ids[64];
    __shared__ int h[NCODE];
    const int t = threadIdx.x;
    const int blk = blockIdx.x;                 // 0..1023
    const int b = blk >> 4;
    const int hw0 = (blk & 15) << 6;

    if (t < 64) ids[t] = idxv[(b << 10) + hw0 + t];
    h[t] = 0;
    if (t < 512) h[t + 512] = 0;
    __syncthreads();

    if (t < 64) atomicAdd(&h[ids[t]], 1);       // completes before next barrier

    // stage 64 gathered E rows: 4096 float4 / 512 thr = 8 iters, coalesced per row
    #pragma unroll
    for (int i = 0; i < 8; ++i) {
        int f = i * 512 + t;                    // float4 id in [64][64]
        int row = f >> 6;
        int c4 = f & 63;
        float4 v = *reinterpret_cast<const float4*>(ew + (size_t)ids[row] * DIMS + c4 * 4);
        float2 lo2 = {v.x, v.y};
        float2 hi2 = {v.z, v.w};
        *reinterpret_cast<float2*>(&Eq[row * QSTRIDE + c4 * 4]) = lo2;
        *reinterpret_cast<float2*>(&Eq[row * QSTRIDE + c4 * 4 + 2]) = hi2;
    }
    __syncthreads();

    // thread handles a float4 of 4 consecutive points (q4) at channel cb + k*32
    const int q4 = t & 15;                      // point-quad: points 4*q4..4*q4+3
    const int cb = t >> 4;                      // 0..31
    const int p = q4 * 4;
    float lsum = 0.0f;
    #pragma unroll
    for (int k = 0; k < 8; ++k) {
        int c = k * 32 + cb;
        unsigned g = ((unsigned)b << 18) | ((unsigned)c << 10) | (unsigned)(hw0 + p);
        float4 xv = *reinterpret_cast<const float4*>(x + g);   // 16B aligned
        float q0 = Eq[(p + 0) * QSTRIDE + c];
        float q1 = Eq[(p + 1) * QSTRIDE + c];
        float q2 = Eq[(p + 2) * QSTRIDE + c];
        float q3 = Eq[(p + 3) * QSTRIDE + c];
        float d0 = q0 - xv.x, d1 = q1 - xv.y, d2 = q2 - xv.z, d3 = q3 - xv.w;
        float4 o;
        o.x = xv.x + d0; o.y = xv.y + d1; o.z = xv.z + d2; o.w = xv.w + d3;
        // out+1+g is dword-aligned only -> unaligned vector store (dwordx4)
        *reinterpret_cast<float4_u*>(out + OUT_Q_OFF + g) = o;
        lsum += d0 * d0 + d1 * d1 + d2 * d2 + d3 * d3;
    }
    #pragma unroll
    for (int off = 32; off > 0; off >>= 1) lsum += __shfl_down(lsum, off);
    if ((t & 63) == 0) atomicAdd(&loss_acc[blk & 63], lsum);

    // flush histogram (h finalized before the staging barrier) + idx floats
    int v0 = h[t];
    if (v0) atomicAdd(&counts[t], v0);
    if (t < 512) {
        int v1 = h[t + 512];
        if (v1) atomicAdd(&counts[t + 512], v1);
    }
    if (t < 64) out[OUT_IDX_OFF + (b << 10) + hw0 + t] = (float)ids[t];
}

// ---------------------------------------------------------------------------
// Perplexity + final loss.
__global__ __launch_bounds__(256) void k_final(const int* __restrict__ counts,
                                               const float* __restrict__ loss_acc,
                                               float* __restrict__ out) {
    int t = threadIdx.x;
    float s = 0.0f;
    #pragma unroll
    for (int i = 0; i < 4; ++i) {
        int cnt = counts[t + 256 * i];
        float p = (float)cnt * (1.0f / 65536.0f);
        s += p * logf(p + 1e-10f);
    }
    #pragma unroll
    for (int off = 32; off > 0; off >>= 1) s += __shfl_down(s, off);
    __shared__ float wsum[4];
    if ((t & 63) == 0) wsum[t >> 6] = s;
    __syncthreads();
    if (t == 0) {
        float S = wsum[0] + wsum[1] + wsum[2] + wsum[3];
        out[OUT_PERP_OFF] = expf(-S);
        float ls = 0.0f;
        for (int i = 0; i < 64; ++i) ls += loss_acc[i];
        out[0] = 0.25f * (ls * (1.0f / 16777216.0f));
    }
}

// ---------------------------------------------------------------------------
extern "C" void kernel_launch(void* const* d_in, const int* in_sizes, int n_in,
                              void* d_out, int out_size, void* d_ws, size_t ws_size,
                              hipStream_t stream) {
    const float* x = (const float*)d_in[0];    // [64,256,32,32]
    const float* ew = (const float*)d_in[1];   // [1024,256]
    float* out = (float*)d_out;
    float* ws = (float*)d_ws;

    float* loss_acc = ws;                      // 64 floats
    int* counts = (int*)(ws + 64);             // 1024 ints
    float* enorm = ws + 64 + 1024;             // 1024 floats
    int* idxv = (int*)(ws + 64 + 2048);        // 65536 ints

    // f16 hi/lo staged planes parked in the quantized out region (overwritten by k_quant)
    char* ehi = (char*)(out + EHI_F32_OFF);
    char* elo = (char*)(out + ELO_F32_OFF);

    hipMemsetAsync(d_ws, 0, (64 + 1024) * sizeof(float), stream);

    k_eprep<<<256, 256, 0, stream>>>(ew, ehi, elo, enorm);
    k_argmin_mfma<<<256, 512, 0, stream>>>(x, ehi, elo, enorm, idxv);
    k_quant<<<1024, 512, 0, stream>>>(x, ew, idxv, out, loss_acc, counts);
    k_final<<<1, 256, 0, stream>>>(counts, loss_acc, out);
}

// Round 20
// 162.947 us; speedup vs baseline: 1.0312x; 1.0244x over previous
//
#include <hip/hip_runtime.h>
#include <hip/hip_bf16.h>
#include <math.h>

typedef _Float16 f16;
typedef __attribute__((ext_vector_type(8))) _Float16 f16x8;
typedef __attribute__((ext_vector_type(16))) float f32x16;
typedef float4 float4_u __attribute__((aligned(4)));   // dword-aligned vector store

// Problem constants
#define DIMS 256
#define NCODE 1024
#define NPTS 65536          // 64 * 32 * 32

// d_out layout (floats): [0]=loss, [1..16777217)=quantized NCHW (2^24 elems),
// [16777217]=perplexity, [16777218..16842754)=idx as float (65536)
#define OUT_Q_OFF 1
#define OUT_PERP_OFF 16777217
#define OUT_IDX_OFF 16777218

// E hi/lo f16 planes parked inside the (later overwritten) quantized out region.
// Staged order (both planes): per 64-code tile (32768 B), row=code&63 (512 B),
// granule g=dim>>3 at position g^(row&7) -> linear global_load_lds + swizzled ds_read.
#define EHI_F32_OFF 4
#define ELO_F32_OFF (4 + 131072)
#define TILE2 32768          // bytes per 64-code tile per plane
#define BUFB 65536           // one LDS buffer = [EH 32KB | EL 32KB]

#define XSTRIDE 132         // fp32 per padded LDS row for X transpose chunks (128 pts + pad)

// Direct HBM/L2 -> LDS copy, 16 B per lane; LDS dest = uniform base + lane*16.
__device__ __forceinline__ void gload_lds16(const void* g, void* l) {
    __builtin_amdgcn_global_load_lds(
        (const __attribute__((address_space(1))) unsigned int*)g,
        (__attribute__((address_space(3))) unsigned int*)l, 16, 0, 0);
}

// ---------------------------------------------------------------------------
// Fused E-prep: split E into f16 hi/lo planes (64-code staged/swizzled order)
// + ||e||^2. One wave per codebook row. 256 blocks x 256 thr (4 waves).
__global__ __launch_bounds__(256) void k_eprep(const float* __restrict__ ew,
                                               char* __restrict__ ehi,
                                               char* __restrict__ elo,
                                               float* __restrict__ enorm) {
    int w = threadIdx.x >> 6;
    int l = threadIdx.x & 63;
    int row = blockIdx.x * 4 + w;
    float4 v = *reinterpret_cast<const float4*>(ew + (size_t)row * DIMS + l * 4);
    float vv[4] = {v.x, v.y, v.z, v.w};
    __align__(8) f16 hh[4];
    __align__(8) f16 ll[4];
    float s = 0.0f;
    #pragma unroll
    for (int e = 0; e < 4; ++e) {
        f16 h = (f16)vv[e];
        hh[e] = h;
        ll[e] = (f16)(vv[e] - (float)h);
        s += vv[e] * vv[e];
    }
    // lane l covers dims 4l..4l+3 -> granule g = l>>1, half (l&1)
    size_t off = (size_t)(row >> 6) * TILE2 + (size_t)(row & 63) * 512
               + (size_t)((((l >> 1) ^ (row & 7)) << 4) + ((l & 1) << 3));
    *reinterpret_cast<float2*>(ehi + off) = *reinterpret_cast<float2*>(hh);
    *reinterpret_cast<float2*>(elo + off) = *reinterpret_cast<float2*>(ll);
    #pragma unroll
    for (int off2 = 32; off2 > 0; off2 >>= 1) s += __shfl_down(s, off2);
    if (l == 0) enorm[row] = s;
}

// ---------------------------------------------------------------------------
// MFMA argmin, ONE 8-wave block per CU (grid 256). TK=64 codes/round -> only
// 16 rounds/barriers (halved phase count — the one axis 7 null variants never
// touched). Double-buffered 64KB tiles, 1 barrier/round, dual acc (codes
// lrow / lrow+32), acc init = -0.5*||e||^2 (argmax, compare-only tail).
__global__ __launch_bounds__(512, 1) void k_argmin_mfma(const float* __restrict__ x,
                                                        const char* __restrict__ ehi,
                                                        const char* __restrict__ elo,
                                                        const float* __restrict__ enorm,
                                                        int* __restrict__ out_idx) {
    __shared__ __align__(16) char smem[2 * BUFB];   // 131072 B
    __shared__ float enorm_lds[NCODE];
    float* Xs = (float*)smem;                   // phase 1 reuse: [64][XSTRIDE] fp32 (33792 B)

    const int t = threadIdx.x;                  // 0..511
    const int wave = t >> 6;                    // 0..7
    const int lane = t & 63;
    const int lrow = lane & 31;
    const int lhalf = lane >> 5;

    const int blk = blockIdx.x;                 // 0..255
    const int b = blk >> 2;                     // batch
    const int hw0 = (blk & 3) << 8;             // 256-point slab within batch
    const float* xb = x + (size_t)b * (DIMS * 1024) + hw0;

    // stage enorm into LDS (covered by the phase-1 barriers)
    enorm_lds[t] = enorm[t];
    enorm_lds[t + 512] = enorm[t + 512];

    // ---- Phase 1: build split-f16 A fragments (two 128-point halves) ----
    f16x8 ahi[16], alo[16];
    #pragma unroll
    for (int dc = 0; dc < 4; ++dc) {
        #pragma unroll
        for (int h = 0; h < 2; ++h) {
            __syncthreads();
            // stage 64 dims x 128 pts fp32: 2048 float4 / 512 thr = 4 iters
            #pragma unroll
            for (int i = 0; i < 4; ++i) {
                int id = i * 512 + t;
                int d = id >> 5;                // 0..63
                int p4 = id & 31;               // float4 within the 128-pt half
                float4 v = *reinterpret_cast<const float4*>(
                    xb + (size_t)(dc * 64 + d) * 1024 + h * 128 + p4 * 4);
                *reinterpret_cast<float4*>(&Xs[d * XSTRIDE + p4 * 4]) = v;
            }
            __syncthreads();
            if ((wave >> 2) == h) {
                int p = (wave & 3) * 32 + lrow;
                #pragma unroll
                for (int kcl = 0; kcl < 4; ++kcl) {
                    f16x8 hh, ll;
                    #pragma unroll
                    for (int e = 0; e < 8; ++e) {
                        float xv = Xs[(kcl * 16 + lhalf * 8 + e) * XSTRIDE + p];
                        f16 hi = (f16)xv;
                        hh[e] = hi;
                        ll[e] = (f16)(xv - (float)hi);
                    }
                    ahi[dc * 4 + kcl] = hh;
                    alo[dc * 4 + kcl] = ll;
                }
            }
        }
    }
    __syncthreads();    // all waves done reading Xs before buf0 staging lands

    // ---- staging assignment: waves 0-3 -> EH plane, waves 4-7 -> EL plane;
    //      each wave stages 8 KB of a 32 KB plane (8 loads of 1 KB).
    const int plane = wave >> 2;
    const char* gplane = plane ? elo : ehi;
    const int pl_off = plane * TILE2;                // within a buffer
    const int woff = (wave & 3) * 8192;

    // ---- Prologue: stage tile 0 into buffer 0 ----
    #pragma unroll
    for (int i = 0; i < 8; ++i) {
        int off = woff + i * 1024;
        gload_lds16(gplane + off + lane * 16, smem + pl_off + off);
    }
    __syncthreads();    // implicit vmcnt(0): buf0 ready

    float bestv[16];
    int besti[16];
    #pragma unroll
    for (int r = 0; r < 16; ++r) { bestv[r] = -3.4e38f; besti[r] = 0; }

    // ---- Main loop: 16 rounds of 64 codes, 1 barrier per round ----
    for (int rd = 0; rd < 16; ++rd) {
        // issue next tile's HBM->LDS copies into the other buffer (no regs held)
        if (rd + 1 < 16) {
            const char* gp = gplane + (size_t)(rd + 1) * TILE2;
            char* lp = smem + ((rd + 1) & 1) * BUFB + pl_off;
            #pragma unroll
            for (int i = 0; i < 8; ++i) {
                int off = woff + i * 1024;
                gload_lds16(gp + off + lane * 16, lp + off);
            }
        }

        const char* EHb = smem + (rd & 1) * BUFB;
        const char* ELb = EHb + TILE2;
        f32x16 acc0, acc1;
        float nh0 = -0.5f * enorm_lds[rd * 64 + lrow];
        float nh1 = -0.5f * enorm_lds[rd * 64 + 32 + lrow];
        #pragma unroll
        for (int r = 0; r < 16; ++r) { acc0[r] = nh0; acc1[r] = nh1; }

        __builtin_amdgcn_s_setprio(1);
        #pragma unroll
        for (int kc = 0; kc < 16; ++kc) {
            int g = kc * 2 + lhalf;
            int ra = lrow * 512 + ((g ^ (lrow & 7)) << 4);   // swizzled read addr
            f16x8 bh0 = *reinterpret_cast<const f16x8*>(EHb + ra);
            f16x8 bh1 = *reinterpret_cast<const f16x8*>(EHb + ra + 16384);
            f16x8 bl0 = *reinterpret_cast<const f16x8*>(ELb + ra);
            f16x8 bl1 = *reinterpret_cast<const f16x8*>(ELb + ra + 16384);
            acc0 = __builtin_amdgcn_mfma_f32_32x32x16_f16(ahi[kc], bh0, acc0, 0, 0, 0);
            acc1 = __builtin_amdgcn_mfma_f32_32x32x16_f16(ahi[kc], bh1, acc1, 0, 0, 0);
            acc0 = __builtin_amdgcn_mfma_f32_32x32x16_f16(ahi[kc], bl0, acc0, 0, 0, 0);
            acc1 = __builtin_amdgcn_mfma_f32_32x32x16_f16(ahi[kc], bl1, acc1, 0, 0, 0);
            acc0 = __builtin_amdgcn_mfma_f32_32x32x16_f16(alo[kc], bh0, acc0, 0, 0, 0);
            acc1 = __builtin_amdgcn_mfma_f32_32x32x16_f16(alo[kc], bh1, acc1, 0, 0, 0);
        }
        __builtin_amdgcn_s_setprio(0);

        // score: acc0 first (lower codes) then acc1; strict > keeps lowest code
        {
            int cw0 = rd * 64 + lrow;
            int cw1 = cw0 + 32;
            #pragma unroll
            for (int r = 0; r < 16; ++r) {
                float s0 = acc0[r];
                if (s0 > bestv[r]) { bestv[r] = s0; besti[r] = cw0; }
                float s1 = acc1[r];
                if (s1 > bestv[r]) { bestv[r] = s1; besti[r] = cw1; }
            }
        }
        __syncthreads();    // implicit vmcnt(0): next buffer ready; reads of cur done
    }

    // ---- cross-lane argmax reduce over the 32 codes dimension (lrow) ----
    #pragma unroll
    for (int off = 1; off <= 16; off <<= 1) {
        #pragma unroll
        for (int r = 0; r < 16; ++r) {
            float ov = __shfl_xor(bestv[r], off);
            int oi = __shfl_xor(besti[r], off);
            if (ov > bestv[r] || (ov == bestv[r] && oi < besti[r])) {
                bestv[r] = ov;
                besti[r] = oi;
            }
        }
    }
    if (lrow == 0) {
        #pragma unroll
        for (int r = 0; r < 16; ++r) {
            int row = (r & 3) + 8 * (r >> 2) + 4 * lhalf;   // C/D row mapping
            out_idx[blk * 256 + wave * 32 + row] = besti[r];
        }
    }
}

// ---------------------------------------------------------------------------
// Tiled quantize + histogram + idx output (merged; NO fence). Block = 64 pts,
// gather E rows once into LDS, stream x (float4) / out (unaligned dwordx4).
// grid 1024, 512 threads.
#define QSTRIDE 258
__global__ __launch_bounds__(512) void k_quant(const float* __restrict__ x,
                                               const float* __restrict__ ew,
                                               const int* __restrict__ idxv,
                                               float* __restrict__ out,
                                               float* __restrict__ loss_acc,
                                               int* __restrict__ counts) {
    __shared__ float Eq[64 * QSTRIDE];          // 66048 B
    __shared__ int ids[64];
    __shared__ int h[NCODE];
    const int t = threadIdx.x;
    const int blk = blockIdx.x;                 // 0..1023
    const int b = blk >> 4;
    const int hw0 = (blk & 15) << 6;

    if (t < 64) ids[t] = idxv[(b << 10) + hw0 + t];
    h[t] = 0;
    if (t < 512) h[t + 512] = 0;
    __syncthreads();

    if (t < 64) atomicAdd(&h[ids[t]], 1);       // completes before next barrier

    // stage 64 gathered E rows: 4096 float4 / 512 thr = 8 iters, coalesced per row
    #pragma unroll
    for (int i = 0; i < 8; ++i) {
        int f = i * 512 + t;                    // float4 id in [64][64]
        int row = f >> 6;
        int c4 = f & 63;
        float4 v = *reinterpret_cast<const float4*>(ew + (size_t)ids[row] * DIMS + c4 * 4);
        float2 lo2 = {v.x, v.y};
        float2 hi2 = {v.z, v.w};
        *reinterpret_cast<float2*>(&Eq[row * QSTRIDE + c4 * 4]) = lo2;
        *reinterpret_cast<float2*>(&Eq[row * QSTRIDE + c4 * 4 + 2]) = hi2;
    }
    __syncthreads();

    // thread handles a float4 of 4 consecutive points (q4) at channel cb + k*32
    const int q4 = t & 15;                      // point-quad: points 4*q4..4*q4+3
    const int cb = t >> 4;                      // 0..31
    const int p = q4 * 4;
    float lsum = 0.0f;
    #pragma unroll
    for (int k = 0; k < 8; ++k) {
        int c = k * 32 + cb;
        unsigned g = ((unsigned)b << 18) | ((unsigned)c << 10) | (unsigned)(hw0 + p);
        float4 xv = *reinterpret_cast<const float4*>(x + g);   // 16B aligned
        float q0 = Eq[(p + 0) * QSTRIDE + c];
        float q1 = Eq[(p + 1) * QSTRIDE + c];
        float q2 = Eq[(p + 2) * QSTRIDE + c];
        float q3 = Eq[(p + 3) * QSTRIDE + c];
        float d0 = q0 - xv.x, d1 = q1 - xv.y, d2 = q2 - xv.z, d3 = q3 - xv.w;
        float4 o;
        o.x = xv.x + d0; o.y = xv.y + d1; o.z = xv.z + d2; o.w = xv.w + d3;
        // out+1+g is dword-aligned only -> unaligned vector store (dwordx4)
        *reinterpret_cast<float4_u*>(out + OUT_Q_OFF + g) = o;
        lsum += d0 * d0 + d1 * d1 + d2 * d2 + d3 * d3;
    }
    #pragma unroll
    for (int off = 32; off > 0; off >>= 1) lsum += __shfl_down(lsum, off);
    if ((t & 63) == 0) atomicAdd(&loss_acc[blk & 63], lsum);

    // flush histogram (h finalized before the staging barrier) + idx floats
    int v0 = h[t];
    if (v0) atomicAdd(&counts[t], v0);
    if (t < 512) {
        int v1 = h[t + 512];
        if (v1) atomicAdd(&counts[t + 512], v1);
    }
    if (t < 64) out[OUT_IDX_OFF + (b << 10) + hw0 + t] = (float)ids[t];
}

// ---------------------------------------------------------------------------
// Perplexity + final loss.
__global__ __launch_bounds__(256) void k_final(const int* __restrict__ counts,
                                               const float* __restrict__ loss_acc,
                                               float* __restrict__ out) {
    int t = threadIdx.x;
    float s = 0.0f;
    #pragma unroll
    for (int i = 0; i < 4; ++i) {
        int cnt = counts[t + 256 * i];
        float p = (float)cnt * (1.0f / 65536.0f);
        s += p * logf(p + 1e-10f);
    }
    #pragma unroll
    for (int off = 32; off > 0; off >>= 1) s += __shfl_down(s, off);
    __shared__ float wsum[4];
    if ((t & 63) == 0) wsum[t >> 6] = s;
    __syncthreads();
    if (t == 0) {
        float S = wsum[0] + wsum[1] + wsum[2] + wsum[3];
        out[OUT_PERP_OFF] = expf(-S);
        float ls = 0.0f;
        for (int i = 0; i < 64; ++i) ls += loss_acc[i];
        out[0] = 0.25f * (ls * (1.0f / 16777216.0f));
    }
}

// ---------------------------------------------------------------------------
extern "C" void kernel_launch(void* const* d_in, const int* in_sizes, int n_in,
                              void* d_out, int out_size, void* d_ws, size_t ws_size,
                              hipStream_t stream) {
    const float* x = (const float*)d_in[0];    // [64,256,32,32]
    const float* ew = (const float*)d_in[1];   // [1024,256]
    float* out = (float*)d_out;
    float* ws = (float*)d_ws;

    float* loss_acc = ws;                      // 64 floats
    int* counts = (int*)(ws + 64);             // 1024 ints
    float* enorm = ws + 64 + 1024;             // 1024 floats
    int* idxv = (int*)(ws + 64 + 2048);        // 65536 ints

    // f16 hi/lo staged planes parked in the quantized out region (overwritten by k_quant)
    char* ehi = (char*)(out + EHI_F32_OFF);
    char* elo = (char*)(out + ELO_F32_OFF);

    hipMemsetAsync(d_ws, 0, (64 + 1024) * sizeof(float), stream);

    k_eprep<<<256, 256, 0, stream>>>(ew, ehi, elo, enorm);
    k_argmin_mfma<<<256, 512, 0, stream>>>(x, ehi, elo, enorm, idxv);
    k_quant<<<1024, 512, 0, stream>>>(x, ew, idxv, out, loss_acc, counts);
    k_final<<<1, 256, 0, stream>>>(counts, loss_acc, out);
}